// Round 4
// baseline (408.065 us; speedup 1.0000x reference)
//
#include <hip/hip_runtime.h>

#define B_  8
#define C_  256
#define C2_ 128
#define N_  4096
#define LOG2E 1.44269504088896f
#define LD_  136   // fp16 tile row stride: 272B, 16B-aligned vec8, 2-way banks (free)
#define LDF_ 132   // fp32 tile row stride: 528B

typedef _Float16 f16;
typedef _Float16 f16x8 __attribute__((ext_vector_type(8)));
typedef float f32x4  __attribute__((ext_vector_type(4)));

// ---------------------------------------------------------------------------
// Kernel A: conv1 (fp32 in, fp16 out, DUAL layout).
// Y[b,n,c2] = sum_c x[b,c,n]*W1[c2,c] + b1[c2]; also writes Yt[b,c2,n] so the
// attention kernel can read V-fragments (k-major) straight from global/L2.
// Grid (8 b, 32 n-tiles) => blockID%8==b => per-XCD L2 locality.
// ---------------------------------------------------------------------------
__global__ __launch_bounds__(256, 1)
void conv1_kernel(const float* __restrict__ x,
                  const float* __restrict__ W1,
                  const float* __restrict__ b1,
                  f16* __restrict__ Y, f16* __restrict__ Yt)
{
  __shared__ __align__(16) char smem[50176];
  float* Xr = (float*)smem;              // [64][LDF_] staged x chunk
  f16*   Ah = (f16*)(smem + 33792);      // [8][128][8] A-layout fp16
  f16*   T  = (f16*)smem;                // [128][LD_] epilogue transpose (alias)

  const int t = threadIdx.x;
  const int w = t >> 6, lane = t & 63, quad = lane >> 4, l16 = lane & 15;
  const int b = blockIdx.x, nt0 = blockIdx.y;

  f32x4 acc[2][8];
#pragma unroll
  for (int i = 0; i < 2; i++)
#pragma unroll
    for (int j = 0; j < 8; j++) acc[i][j] = (f32x4){0.f, 0.f, 0.f, 0.f};

#pragma unroll 1
  for (int kc = 0; kc < 4; kc++) {
    // stage 64c x 128n fp32, coalesced along n
#pragma unroll
    for (int pass = 0; pass < 8; pass++) {
      int r  = (t >> 5) + pass * 8;           // c_local 0..63
      int c4 = (t & 31) * 4;
      float4 v = *(const float4*)(x + ((long)(b * C_ + kc * 64 + r)) * N_ + nt0 * 128 + c4);
      *(float4*)(&Xr[r * LDF_ + c4]) = v;
    }
    __syncthreads();
    // transpose + cvt fp16 into A-layout [c>>3][n][c&7]
#pragma unroll
    for (int pass = 0; pass < 4; pass++) {
      int n = t & 127;
      int q = (t >> 7) + pass * 2;            // 0..7
      f16x8 vh;
#pragma unroll
      for (int jj = 0; jj < 8; jj++) vh[jj] = (f16)Xr[(q * 8 + jj) * LDF_ + n];
      *(f16x8*)(&Ah[(q * 128 + n) * 8]) = vh;
    }
    __syncthreads();
#pragma unroll
    for (int ks2 = 0; ks2 < 2; ks2++) {
      f16x8 bh[8];
#pragma unroll
      for (int nt = 0; nt < 8; nt++) {
        int c2 = nt * 16 + l16;
        int c  = kc * 64 + ks2 * 32 + quad * 8;
        const float* wp = W1 + c2 * C_ + c;
        float4 f0 = *(const float4*)(wp);
        float4 f1 = *(const float4*)(wp + 4);
        bh[nt][0] = (f16)f0.x; bh[nt][1] = (f16)f0.y; bh[nt][2] = (f16)f0.z; bh[nt][3] = (f16)f0.w;
        bh[nt][4] = (f16)f1.x; bh[nt][5] = (f16)f1.y; bh[nt][6] = (f16)f1.z; bh[nt][7] = (f16)f1.w;
      }
#pragma unroll
      for (int mt = 0; mt < 2; mt++) {
        int n = w * 32 + mt * 16 + l16;
        int q = ks2 * 4 + quad;
        f16x8 ah = *(const f16x8*)(&Ah[(q * 128 + n) * 8]);
#pragma unroll
        for (int nt = 0; nt < 8; nt++)
          acc[mt][nt] = __builtin_amdgcn_mfma_f32_16x16x32_f16(ah, bh[nt], acc[mt][nt], 0, 0, 0);
      }
    }
    __syncthreads();
  }
  // epilogue: +b1, store Y[n][c2] direct; stage T[c2][n] for coalesced Yt
#pragma unroll
  for (int nt = 0; nt < 8; nt++) {
    int c2 = nt * 16 + l16;
    float bv = b1[c2];
#pragma unroll
    for (int mt = 0; mt < 2; mt++)
#pragma unroll
      for (int rg = 0; rg < 4; rg++) {
        int row = w * 32 + mt * 16 + quad * 4 + rg;
        f16 yv = (f16)(acc[mt][nt][rg] + bv);
        Y[((long)b * N_ + nt0 * 128 + row) * C2_ + c2] = yv;
        T[c2 * LD_ + row] = yv;
      }
  }
  __syncthreads();
#pragma unroll
  for (int pass = 0; pass < 8; pass++) {
    int r  = (t >> 4) + pass * 16;            // c2
    int c8 = (t & 15) * 8;                    // n
    f16x8 v = *(const f16x8*)(&T[r * LD_ + c8]);
    *(f16x8*)(Yt + ((long)(b * C2_ + r)) * N_ + nt0 * 128 + c8) = v;
  }
}

// ---------------------------------------------------------------------------
// Kernel B: flash attention, unscaled, Q=K=V=Y (fp16 single-pass).
// Grid (8 b, 32 q-tiles). 128 Q rows/WG, 32 K-tiles of 128.
// Ks double-buffered (1 barrier/iter, staging overlaps compute);
// P is wave-private in Ps (no barrier); V frags read from Yt via L2.
// LDS = 2*34K + 34K = 102 KB.
// ---------------------------------------------------------------------------
__global__ __launch_bounds__(256, 1)
void attn_kernel(const f16* __restrict__ Y, const f16* __restrict__ Yt,
                 f16* __restrict__ O)
{
  __shared__ f16 Ks[2 * 128 * LD_];
  __shared__ f16 Ps[128 * LD_];

  const int t = threadIdx.x;
  const int w = t >> 6, lane = t & 63, quad = lane >> 4, l16 = lane & 15;
  const int b = blockIdx.x, qt = blockIdx.y;
  const f16* Yb  = Y  + (long)b * N_ * C2_;
  const f16* Ytb = Yt + (long)b * C2_ * N_;
  f16* Ob = O + (long)b * N_ * C2_;

  const int sr = (t >> 4);            // staging row base (0..15)
  const int sc = (t & 15) * 8;        // staging col

  // Q fragments straight from global (stay in registers all kernel)
  f16x8 qf[2][4];
#pragma unroll
  for (int mt = 0; mt < 2; mt++)
#pragma unroll
    for (int ks = 0; ks < 4; ks++)
      qf[mt][ks] = *(const f16x8*)(Yb + (long)(qt * 128 + w * 32 + mt * 16 + l16) * C2_ + ks * 32 + quad * 8);

  f32x4 Oa[2][8];
#pragma unroll
  for (int i = 0; i < 2; i++)
#pragma unroll
    for (int j = 0; j < 8; j++) Oa[i][j] = (f32x4){0.f, 0.f, 0.f, 0.f};
  float mrun[2][4], lrun[2][4];
#pragma unroll
  for (int i = 0; i < 2; i++)
#pragma unroll
    for (int j = 0; j < 4; j++) { mrun[i][j] = -1e30f; lrun[i][j] = 0.f; }

  // prologue: stage K-tile 0 into buffer 0
#pragma unroll
  for (int pass = 0; pass < 8; pass++) {
    int r = sr + pass * 16;
    *(f16x8*)(&Ks[r * LD_ + sc]) = *(const f16x8*)(Yb + (long)r * C2_ + sc);
  }

#pragma unroll 1
  for (int kt = 0; kt < 32; kt++) {
    f16* Kc = &Ks[(kt & 1) * 128 * LD_];
    f16* Kn = &Ks[((kt + 1) & 1) * 128 * LD_];
    __syncthreads();   // Kc fully staged; all waves done reading Kn's old data

    // issue next-tile staging loads (hide latency under S-compute)
    f16x8 st[8];
    if (kt + 1 < 32) {
#pragma unroll
      for (int pass = 0; pass < 8; pass++) {
        int r = sr + pass * 16;
        st[pass] = *(const f16x8*)(Yb + (long)((kt + 1) * 128 + r) * C2_ + sc);
      }
    }

    // S = Q K^T (fp32 accum)
    f32x4 S[2][8];
#pragma unroll
    for (int i = 0; i < 2; i++)
#pragma unroll
      for (int j = 0; j < 8; j++) S[i][j] = (f32x4){0.f, 0.f, 0.f, 0.f};
#pragma unroll
    for (int ks = 0; ks < 4; ks++) {
      f16x8 bfr[8];
#pragma unroll
      for (int nt = 0; nt < 8; nt++)
        bfr[nt] = *(const f16x8*)(&Kc[(nt * 16 + l16) * LD_ + ks * 32 + quad * 8]);
#pragma unroll
      for (int mt = 0; mt < 2; mt++)
#pragma unroll
        for (int nt = 0; nt < 8; nt++)
          S[mt][nt] = __builtin_amdgcn_mfma_f32_16x16x32_f16(qf[mt][ks], bfr[nt], S[mt][nt], 0, 0, 0);
    }

    // write staged next tile (writes to Kn race nothing: reads of Kn ended at barrier)
    if (kt + 1 < 32) {
#pragma unroll
      for (int pass = 0; pass < 8; pass++)
        *(f16x8*)(&Kn[(sr + pass * 16) * LD_ + sc]) = st[pass];
    }

    // online softmax (rows = quad*4+rg; butterfly over 16 lanes)
#pragma unroll
    for (int mt = 0; mt < 2; mt++)
#pragma unroll
      for (int rg = 0; rg < 4; rg++) {
        float smax = S[mt][0][rg];
#pragma unroll
        for (int nt = 1; nt < 8; nt++) smax = fmaxf(smax, S[mt][nt][rg]);
#pragma unroll
        for (int off = 8; off >= 1; off >>= 1) smax = fmaxf(smax, __shfl_xor(smax, off));
        float newm = fmaxf(mrun[mt][rg], smax);
        float alpha = exp2f(fminf((mrun[mt][rg] - newm) * LOG2E, 0.f));
        mrun[mt][rg] = newm;
        float ps = 0.f;
#pragma unroll
        for (int nt = 0; nt < 8; nt++) {
          float p = exp2f(fminf((S[mt][nt][rg] - newm) * LOG2E, 0.f));
          S[mt][nt][rg] = p;
          ps += p;
        }
#pragma unroll
        for (int off = 8; off >= 1; off >>= 1) ps += __shfl_xor(ps, off);
        lrun[mt][rg] = lrun[mt][rg] * alpha + ps;
#pragma unroll
        for (int dt = 0; dt < 8; dt++) Oa[mt][dt][rg] *= alpha;
      }

    // write P (fp16) — wave-private rows of Ps, no barrier needed
#pragma unroll
    for (int mt = 0; mt < 2; mt++)
#pragma unroll
      for (int nt = 0; nt < 8; nt++)
#pragma unroll
        for (int rg = 0; rg < 4; rg++) {
          int r = w * 32 + mt * 16 + quad * 4 + rg;
          Ps[r * LD_ + nt * 16 + l16] = (f16)S[mt][nt][rg];
        }

    // O += P V ; V fragments direct from Yt (global/L2, k-major rows)
#pragma unroll
    for (int ks = 0; ks < 4; ks++) {
      f16x8 vb[8];
#pragma unroll
      for (int dt = 0; dt < 8; dt++)
        vb[dt] = *(const f16x8*)(Ytb + (long)(dt * 16 + l16) * N_ + kt * 128 + ks * 32 + quad * 8);
      f16x8 pa[2];
#pragma unroll
      for (int mt = 0; mt < 2; mt++)
        pa[mt] = *(const f16x8*)(&Ps[(w * 32 + mt * 16 + l16) * LD_ + ks * 32 + quad * 8]);
#pragma unroll
      for (int mt = 0; mt < 2; mt++)
#pragma unroll
        for (int dt = 0; dt < 8; dt++)
          Oa[mt][dt] = __builtin_amdgcn_mfma_f32_16x16x32_f16(pa[mt], vb[dt], Oa[mt][dt], 0, 0, 0);
    }
  }
  // epilogue: O /= l, store fp16
#pragma unroll
  for (int mt = 0; mt < 2; mt++)
#pragma unroll
    for (int rg = 0; rg < 4; rg++) {
      float inv = 1.0f / fmaxf(lrun[mt][rg], 1e-20f);
      int r = w * 32 + mt * 16 + quad * 4 + rg;
#pragma unroll
      for (int dt = 0; dt < 8; dt++)
        Ob[(long)(qt * 128 + r) * C2_ + dt * 16 + l16] = (f16)(Oa[mt][dt][rg] * inv);
    }
}

// ---------------------------------------------------------------------------
// Kernel C: conv2 + scale + residual (fp32 out). torch .view == reinterpret
// O[b] as [128][4096] row-major. out = (W2·view + b2)*scale + x.
// ---------------------------------------------------------------------------
__global__ __launch_bounds__(256, 1)
void conv2_kernel(const f16* __restrict__ O,
                  const float* __restrict__ W2,
                  const float* __restrict__ b2,
                  const float* __restrict__ scale,
                  const float* __restrict__ x,
                  float* __restrict__ out)
{
  __shared__ f16 Or[128 * LD_];
  __shared__ f16 Bsw[16 * 128 * 8];

  const int t = threadIdx.x;
  const int w = t >> 6, lane = t & 63, quad = lane >> 4, l16 = lane & 15;
  const int b = blockIdx.x, pt = blockIdx.y;
  const f16* Obv = O + (long)b * N_ * C2_;  // view [128][4096]

#pragma unroll
  for (int pass = 0; pass < 8; pass++) {
    int r = (t >> 4) + pass * 16, c8 = (t & 15) * 8;
    *(f16x8*)(&Or[r * LD_ + c8]) = *(const f16x8*)(Obv + (long)r * N_ + pt * 128 + c8);
  }
  __syncthreads();
#pragma unroll
  for (int pass = 0; pass < 8; pass++) {
    int p = t & 127;
    int q = (t >> 7) + pass * 2;
    f16x8 vv;
#pragma unroll
    for (int jj = 0; jj < 8; jj++) vv[jj] = Or[(q * 8 + jj) * LD_ + p];
    *(f16x8*)(&Bsw[(q * 128 + p) * 8]) = vv;
  }
  __syncthreads();

  f32x4 acc[4][8];
#pragma unroll
  for (int i = 0; i < 4; i++)
#pragma unroll
    for (int j = 0; j < 8; j++) acc[i][j] = (f32x4){0.f, 0.f, 0.f, 0.f};

#pragma unroll
  for (int ks = 0; ks < 4; ks++) {
    f16x8 bfr[8];
#pragma unroll
    for (int nt = 0; nt < 8; nt++)
      bfr[nt] = *(const f16x8*)(&Bsw[((ks * 4 + quad) * 128 + nt * 16 + l16) * 8]);
#pragma unroll
    for (int mt = 0; mt < 4; mt++) {
      int o = w * 64 + mt * 16 + l16;
      const float* wp = W2 + o * C2_ + ks * 32 + quad * 8;
      float4 f0 = *(const float4*)(wp);
      float4 f1 = *(const float4*)(wp + 4);
      f16x8 ah;
      ah[0] = (f16)f0.x; ah[1] = (f16)f0.y; ah[2] = (f16)f0.z; ah[3] = (f16)f0.w;
      ah[4] = (f16)f1.x; ah[5] = (f16)f1.y; ah[6] = (f16)f1.z; ah[7] = (f16)f1.w;
#pragma unroll
      for (int nt = 0; nt < 8; nt++)
        acc[mt][nt] = __builtin_amdgcn_mfma_f32_16x16x32_f16(ah, bfr[nt], acc[mt][nt], 0, 0, 0);
    }
  }
#pragma unroll
  for (int mt = 0; mt < 4; mt++)
#pragma unroll
    for (int rg = 0; rg < 4; rg++) {
      int o = w * 64 + mt * 16 + quad * 4 + rg;
      float so = scale[o], bo = b2[o];
#pragma unroll
      for (int nt = 0; nt < 8; nt++) {
        int p = pt * 128 + nt * 16 + l16;
        long xo = ((long)b * C_ + o) * N_ + p;
        out[xo] = (acc[mt][nt][rg] + bo) * so + x[xo];
      }
    }
}

extern "C" void kernel_launch(void* const* d_in, const int* in_sizes, int n_in,
                              void* d_out, int out_size, void* d_ws, size_t ws_size,
                              hipStream_t stream) {
  const float* x     = (const float*)d_in[0];
  const float* W1    = (const float*)d_in[1];
  const float* b1    = (const float*)d_in[2];
  const float* W2    = (const float*)d_in[3];
  const float* b2    = (const float*)d_in[4];
  const float* scale = (const float*)d_in[5];
  float* outp = (float*)d_out;

  f16* Y  = (f16*)d_ws;                          // [8][4096][128] fp16 (8 MiB)
  f16* Yt = Y  + (size_t)B_ * N_ * C2_;          // [8][128][4096] fp16 (8 MiB)
  f16* O  = Yt + (size_t)B_ * N_ * C2_;          // [8][4096][128] fp16 (8 MiB)

  dim3 grid(8, 32), blk(256);                    // x=b => blockID%8==b => XCD-local L2
  conv1_kernel<<<grid, blk, 0, stream>>>(x, W1, b1, Y, Yt);
  attn_kernel <<<grid, blk, 0, stream>>>(Y, Yt, O);
  conv2_kernel<<<grid, blk, 0, stream>>>(O, W2, b2, scale, x, outp);
}